// Round 6
// baseline (24.222 us; speedup 1.0000x reference)
//
#include <hip/hip_runtime.h>

// MakeCutouts: 32 random crops (sz in [224,511]) of a [2,3,512,512] fp32
// image, each adaptive-avg-pooled (PyTorch semantics) to 224x224.
// Output: [32*2, 3, 224, 224] fp32.
//
// R5 (on top of R4's cooperative row structure):
//  - XCD-affine decode: bid%8 = XCD (round-robin dispatch heuristic), each
//    XCD owns 4 whole cutouts, i-major. Adjacent output rows (which share
//    input rows, dy<=4) now hit the same XCD's L2; each input byte is read
//    by exactly one XCD -> L3 read traffic ~170 MB -> ~104 MB.
//  - float2 global loads via even-aligned window (ox&~1, parity shift),
//    halving load-instruction count. Guard (2t-shift) < sz keeps the
//    furthest touched column at ox+sz <= 511 (parity argument), no OOB.

constexpr int CUT   = 224;
constexpr int BC    = 6;          // B*C = 2*3
constexpr int HH    = 512;
constexpr int WW    = 512;
constexpr int PIX   = CUT * CUT;  // 50176
constexpr int PLANE = HH * WW;
constexpr int NCUT  = 32;
constexpr int NXCD  = 8;
constexpr int CPX   = NCUT / NXCD;   // 4 cutouts per XCD

__global__ __launch_bounds__(256) void cutout_kernel(
    const float* __restrict__ in,     // [6, 512, 512] planes
    const int*   __restrict__ sizes,  // [32]
    const int*   __restrict__ offx,   // [32]
    const int*   __restrict__ offy,   // [32]
    float*       __restrict__ out)    // [32, 6, 224, 224] flat
{
    __shared__ float2 vsum[3][WW];    // [plane-pair][crop col] = 12 KB

    // XCD-affine decode (perf heuristic only; any mapping is correct).
    const int bid = blockIdx.x;
    const int xcd = bid & 7;
    const int idx = bid >> 3;            // 0..895
    const int nl  = idx / CUT;           // 0..3
    const int i   = idx - nl * CUT;      // output row, i-major per cutout
    const int n   = xcd * CPX + nl;      // cutout

    const int t = threadIdx.x;

    const int sz = sizes[n];             // uniform -> scalar
    const int oy = offy[n];
    const int ox = offx[n];

    const int sy = (i * sz) / CUT;                        // uniform
    const int dy = ((i + 1) * sz + CUT - 1) / CUT - sy;   // 1..4, uniform

    const int ox2   = ox & ~1;           // even-aligned load window
    const int shift = ox & 1;
    const int c     = 2 * t - shift;     // crop-relative col of .x lane

    // Phase 1: vertical sums over dy rows, 2 cols per thread via float2.
    const bool cg = c < sz;              // lane participates
    const float2* __restrict__ base =
        (const float2*)(in + (oy + sy) * WW + ox2) + t;  // 8B-aligned

    float2 a0{0,0}, a1{0,0}, a2{0,0}, a3{0,0}, a4{0,0}, a5{0,0};
    for (int r = 0; r < dy; ++r) {       // uniform trip count
        const float2* __restrict__ rp = base + r * (WW / 2);
        if (cg) {
            const float2 v0 = rp[0 * PLANE / 2];
            const float2 v1 = rp[1 * PLANE / 2];
            const float2 v2 = rp[2 * PLANE / 2];
            const float2 v3 = rp[3 * PLANE / 2];
            const float2 v4 = rp[4 * PLANE / 2];
            const float2 v5 = rp[5 * PLANE / 2];
            a0.x += v0.x; a0.y += v0.y;  a1.x += v1.x; a1.y += v1.y;
            a2.x += v2.x; a2.y += v2.y;  a3.x += v3.x; a3.y += v3.y;
            a4.x += v4.x; a4.y += v4.y;  a5.x += v5.x; a5.y += v5.y;
        }
    }
    if (cg) {
        if (c >= 0) {                    // only t==0 with shift==1 fails
            vsum[0][c] = make_float2(a0.x, a1.x);
            vsum[1][c] = make_float2(a2.x, a3.x);
            vsum[2][c] = make_float2(a4.x, a5.x);
        }
        // c+1 <= 511 always; cols >= sz hold garbage but are never read.
        vsum[0][c + 1] = make_float2(a0.y, a1.y);
        vsum[1][c + 1] = make_float2(a2.y, a3.y);
        vsum[2][c + 1] = make_float2(a4.y, a5.y);
    }
    __syncthreads();

    // Phase 2: horizontal pooling from LDS, 4 predicated taps (dx in 1..4).
    if (t < CUT) {
        const int sx = (t * sz) / CUT;                        // crop-relative
        const int dx = ((t + 1) * sz + CUT - 1) / CUT - sx;   // 1..4
        const int x1 = sx + (dx > 1 ? 1 : 0);                 // clamped taps
        const int x2 = x1 + (dx > 2 ? 1 : 0);
        const int x3 = x2 + (dx > 3 ? 1 : 0);
        const float w1 = dx > 1 ? 1.f : 0.f;
        const float w2 = dx > 2 ? 1.f : 0.f;
        const float w3 = dx > 3 ? 1.f : 0.f;
        const float rr = __builtin_amdgcn_rcpf((float)(dy * dx));

        float* o = out + (size_t)n * BC * PIX + i * CUT + t;
        #pragma unroll
        for (int pr = 0; pr < 3; ++pr) {
            const float2 v0 = vsum[pr][sx];
            const float2 v1 = vsum[pr][x1];
            const float2 v2 = vsum[pr][x2];
            const float2 v3 = vsum[pr][x3];
            const float se = v0.x + w1 * v1.x + w2 * v2.x + w3 * v3.x;
            const float so = v0.y + w1 * v1.y + w2 * v2.y + w3 * v3.y;
            __builtin_nontemporal_store(se * rr, o + (2 * pr    ) * PIX);
            __builtin_nontemporal_store(so * rr, o + (2 * pr + 1) * PIX);
        }
    }
}

extern "C" void kernel_launch(void* const* d_in, const int* in_sizes, int n_in,
                              void* d_out, int out_size, void* d_ws, size_t ws_size,
                              hipStream_t stream) {
    const float* in    = (const float*)d_in[0];
    const int*   sizes = (const int*)d_in[1];
    const int*   offx  = (const int*)d_in[2];
    const int*   offy  = (const int*)d_in[3];
    float*       out   = (float*)d_out;

    cutout_kernel<<<dim3(NXCD * CPX * CUT), dim3(256), 0, stream>>>(
        in, sizes, offx, offy, out);
}